// Round 5
// baseline (99.440 us; speedup 1.0000x reference)
//
#include <hip/hip_runtime.h>
#include <hip/hip_bf16.h>

typedef __attribute__((ext_vector_type(8))) short short8;
typedef __attribute__((ext_vector_type(4))) float floatx4;

#define NROWS 4096
#define NHALF 2048
#define DDIM  128
#define LDST  136                 // LDS row stride in ushorts (128 + 8 pad -> 272B)
#define SQRT_SCALE 2.6857914f     // sqrt(1/(0.2*ln2)) ; dot of stored z == (sim/T)*log2(e)
#define LN2 0.69314718056f

// ws float layout: [0]=loss acc, [1]=all_num, [2]=k_loss completion counter,
// part [64, 64+4*32*4096) : part[l][k][n] = sum_{m in col-tile k} exp2(z_n . z_m)
//   slot k = column-tile index; written by EXACTLY ONE block (row-side if k>=I_n,
//   col-side if k<I_n) -> plain stores, no zero-init, no atomics.
#define WS_PART_OFF 64
#define WS_DIAG_OFF 524352        // 64 + 4*32*4096
#define WS_POS_OFF  540736        // + 16384
#define WS_Z_BYTE_OFF 2228480     // (WS_POS_OFF + 16384)*4, 16B aligned

__device__ inline unsigned short f2bf(float f) {
    unsigned u = __builtin_bit_cast(unsigned, f);
    u += 0x7fffu + ((u >> 16) & 1u);          // RNE
    return (unsigned short)(u >> 16);
}

// ---------------- kernel 1: normalize + scale + cast to bf16; zero scalars; all_num --------
__global__ __launch_bounds__(256) void k_norm(const float* __restrict__ emb_i,
                                              const float* __restrict__ emb_j,
                                              const float* __restrict__ jv,
                                              float* __restrict__ wsf,
                                              unsigned short* __restrict__ z) {
    int bx = blockIdx.x, tid = threadIdx.x;
    if (bx == 4096) {                         // all_num = sum(joint_valid)
        __shared__ float sred[256];
        float s = 0.f;
        #pragma unroll
        for (int i = 0; i < 8; ++i) s += jv[tid + 256 * i];
        sred[tid] = s; __syncthreads();
        for (int off = 128; off > 0; off >>= 1) {
            if (tid < off) sred[tid] += sred[tid + off];
            __syncthreads();
        }
        if (tid == 0) wsf[1] = sred[0];
        return;
    }
    if (bx == 0 && tid == 0) { wsf[0] = 0.f; *(unsigned*)&wsf[2] = 0u; }

    int wave = tid >> 6, lane = tid & 63;
    int r = bx * 4 + wave;                    // global row 0..16383
    int l = r >> 12, n = r & 4095;
    const float* src = (n < NHALF) ? (emb_i + ((size_t)l * NHALF + n) * DDIM)
                                   : (emb_j + ((size_t)l * NHALF + (n - NHALF)) * DDIM);
    float2 v = *(const float2*)(src + lane * 2);
    float ss = v.x * v.x + v.y * v.y;
    #pragma unroll
    for (int off = 1; off < 64; off <<= 1) ss += __shfl_xor(ss, off);
    float inv = SQRT_SCALE / fmaxf(sqrtf(ss), 1e-12f);
    unsigned pack = ((unsigned)f2bf(v.y * inv) << 16) | (unsigned)f2bf(v.x * inv);
    *(unsigned*)(z + (size_t)r * DDIM + lane * 2) = pack;
}

// ---------------- kernel 2: paired symmetric sim + exp2 partial sums, ZERO atomics ---------
// R4 post-mortem: k_sim ~21us but throughput content ~4us -> stall-bound. Two fixes:
// (a) no atomics: part[l][k][n] has a unique writer (see layout comment above);
// (b) pair the two tiles (I0,J),(I1,J) sharing J in one block: B staged once, the two
//     MFMA/exp2 chains are independent -> ILP fills dependency bubbles; grid 1088 = 1.06
//     residency rounds (was 2112 = 2.06). Singleton (J even, I0=J diag) computes a
//     harmless duplicate tile1 (idempotent diag store, results otherwise unstored) to
//     keep one straight-line basic block.
// Pairs per row J: ceil((J+1)/2); cumulative C(J) = J odd ? ((J+1)/2)^2 : J(J+2)/4; 272/l.
// bx&3 = l pins each XCD (bx%8) to one l -> z working set 1MB, L2-resident.
// launch_bounds(256,3): ~148 live VGPR < 168 cap, no spill (R4: 3 vs 4 waves = neutral).
#define CPAIR(j) (((j) & 1) ? ((((j)+1)>>1)*(((j)+1)>>1)) : (((j)*((j)+2))>>2))
__global__ __launch_bounds__(256, 3) void k_sim(const unsigned short* __restrict__ z,
                                                float* __restrict__ part,
                                                float* __restrict__ diag,
                                                float* __restrict__ pos) {
    __shared__ __align__(16) unsigned short lds[128 * LDST];
    __shared__ float cred[2][4][128];
    int bx = blockIdx.x, tid = threadIdx.x;
    int l = bx & 3, q = bx >> 2;              // q in [0,272)
    int J = (int)(2.f * sqrtf((float)q + 0.25f));
    if (J > 31) J = 31;
    while (J < 31 && CPAIR(J + 1) <= q) ++J;  // guard fp rounding
    while (CPAIR(J) > q) --J;
    int p = q - CPAIR(J);
    int I0 = 2 * p;
    bool two = (2 * p + 1 <= J);
    int I1 = two ? (2 * p + 1) : I0;          // singleton: duplicate tile0 (harmless)

    int wave = tid >> 6, lane = tid & 63, m = lane & 15, quad = lane >> 4;
    const unsigned short* zl = z + (size_t)l * NROWS * DDIM;
    int l4 = l * NROWS;
    int cg0 = J * 128;
    int wr00 = I0 * 128 + wave * 32;          // 32 rows per wave per tile
    int wr10 = I1 * 128 + wave * 32;

    short8 a0[2][4], a1[2][4];
    #pragma unroll
    for (int rs = 0; rs < 2; ++rs) {
        const unsigned short* pa = zl + (size_t)(wr00 + rs * 16 + m) * DDIM + quad * 8;
        #pragma unroll
        for (int kk = 0; kk < 4; ++kk) a0[rs][kk] = *(const short8*)(pa + kk * 32);
    }
    // stage 128x128 bf16 B-tile (cols cg0..cg0+127), shared by BOTH tiles
    #pragma unroll
    for (int i = 0; i < 8; ++i) {
        int chunk = tid + 256 * i;
        int col = chunk >> 4, off = chunk & 15;
        uint4 d = *(const uint4*)(zl + (size_t)(cg0 + col) * DDIM + off * 8);
        *(uint4*)&lds[col * LDST + off * 8] = d;
    }
    #pragma unroll
    for (int rs = 0; rs < 2; ++rs) {
        const unsigned short* pa = zl + (size_t)(wr10 + rs * 16 + m) * DDIM + quad * 8;
        #pragma unroll
        for (int kk = 0; kk < 4; ++kk) a1[rs][kk] = *(const short8*)(pa + kk * 32);
    }
    floatx4 rsum0[2], rsum1[2];
    float csum0[8], csum1[8];
    #pragma unroll
    for (int rs = 0; rs < 2; ++rs) {
        rsum0[rs] = (floatx4){0.f, 0.f, 0.f, 0.f};
        rsum1[rs] = (floatx4){0.f, 0.f, 0.f, 0.f};
    }
    #pragma unroll
    for (int g = 0; g < 8; ++g) { csum0[g] = 0.f; csum1[g] = 0.f; }
    __syncthreads();

    #pragma unroll
    for (int cs = 0; cs < 8; ++cs) {          // 16-col subtiles
        int ct = cg0 + cs * 16;               // tile column base (wave-uniform)
        const unsigned short* lp = &lds[(cs * 16 + m) * LDST + quad * 8];
        short8 b0 = *(const short8*)(lp);
        short8 b1 = *(const short8*)(lp + 32);
        short8 b2 = *(const short8*)(lp + 64);
        short8 b3 = *(const short8*)(lp + 96);
        float t0 = 0.f, t1 = 0.f;
        #pragma unroll
        for (int rs = 0; rs < 2; ++rs) {
            floatx4 p0 = (floatx4){0.f, 0.f, 0.f, 0.f};
            floatx4 p1 = (floatx4){0.f, 0.f, 0.f, 0.f};
            // two independent chains, interleaved for ILP
            p0 = __builtin_amdgcn_mfma_f32_16x16x32_bf16(a0[rs][0], b0, p0, 0, 0, 0);
            p1 = __builtin_amdgcn_mfma_f32_16x16x32_bf16(a1[rs][0], b0, p1, 0, 0, 0);
            p0 = __builtin_amdgcn_mfma_f32_16x16x32_bf16(a0[rs][1], b1, p0, 0, 0, 0);
            p1 = __builtin_amdgcn_mfma_f32_16x16x32_bf16(a1[rs][1], b1, p1, 0, 0, 0);
            p0 = __builtin_amdgcn_mfma_f32_16x16x32_bf16(a0[rs][2], b2, p0, 0, 0, 0);
            p1 = __builtin_amdgcn_mfma_f32_16x16x32_bf16(a1[rs][2], b2, p1, 0, 0, 0);
            p0 = __builtin_amdgcn_mfma_f32_16x16x32_bf16(a0[rs][3], b3, p0, 0, 0, 0);
            p1 = __builtin_amdgcn_mfma_f32_16x16x32_bf16(a1[rs][3], b3, p1, 0, 0, 0);
            int rb0 = wr00 + rs * 16, rb1 = wr10 + rs * 16;
            bool d0 = (ct == rb0), s0 = (ct == rb0 + 2048);
            bool d1 = (ct == rb1), s1 = (ct == rb1 + 2048);
            if (d0 || s0) {                   // rare, wave-uniform
                int c = m - (quad << 2);      // lane holds row rb0+m iff quad*4+c == m
                if (c >= 0 && c < 4) {
                    float v = p0[c];
                    if (d0) diag[l4 + rb0 + m] = v;
                    else { pos[l4 + rb0 + m] = v; pos[l4 + rb0 + m + NHALF] = v; }
                }
            }
            if (d1 || s1) {                   // singleton: d1 duplicates d0 (same value), ok
                int c = m - (quad << 2);
                if (c >= 0 && c < 4) {
                    float v = p1[c];
                    if (d1) diag[l4 + rb1 + m] = v;
                    else { pos[l4 + rb1 + m] = v; pos[l4 + rb1 + m + NHALF] = v; }
                }
            }
            #pragma unroll
            for (int c = 0; c < 4; ++c) {
                float e0 = __builtin_amdgcn_exp2f(p0[c]);
                float e1 = __builtin_amdgcn_exp2f(p1[c]);
                rsum0[rs][c] += e0; t0 += e0;
                rsum1[rs][c] += e1; t1 += e1;
            }
        }
        csum0[cs] += t0;                      // col partials (store-guarded later)
        csum1[cs] += t1;
    }
    // row side: reduce across the 16 column-lanes; plain stores to slot J
    #pragma unroll
    for (int off = 1; off < 16; off <<= 1)
        #pragma unroll
        for (int rs = 0; rs < 2; ++rs)
            #pragma unroll
            for (int c = 0; c < 4; ++c) {
                rsum0[rs][c] += __shfl_xor(rsum0[rs][c], off);
                rsum1[rs][c] += __shfl_xor(rsum1[rs][c], off);
            }
    float* plJ = part + (size_t)(l * 32 + J) * 4096;
    if (m == 0) {                             // lanes 0,16,32,48
        #pragma unroll
        for (int rs = 0; rs < 2; ++rs)
            #pragma unroll
            for (int c = 0; c < 4; ++c) {
                plJ[wr00 + rs * 16 + quad * 4 + c] = rsum0[rs][c];
                if (two) plJ[wr10 + rs * 16 + quad * 4 + c] = rsum1[rs][c];
            }
    }
    // col side (transpose contribution): per-tile slots I0 / I1, skip diag tiles
    #pragma unroll
    for (int g = 0; g < 8; ++g) {             // finish reduce over 16 rows (lane bits 4,5)
        float v0 = csum0[g]; v0 += __shfl_xor(v0, 16); v0 += __shfl_xor(v0, 32);
        float v1 = csum1[g]; v1 += __shfl_xor(v1, 16); v1 += __shfl_xor(v1, 32);
        if (quad == 0) { cred[0][wave][g * 16 + m] = v0; cred[1][wave][g * 16 + m] = v1; }
    }
    __syncthreads();
    if (tid < 128) {
        if (I0 != J) {
            float s = cred[0][0][tid] + cred[0][1][tid] + cred[0][2][tid] + cred[0][3][tid];
            part[(size_t)(l * 32 + I0) * 4096 + cg0 + tid] = s;
        }
    } else {
        if (two && I1 != J) {
            int t = tid - 128;
            float s = cred[1][0][t] + cred[1][1][t] + cred[1][2][t] + cred[1][3][t];
            part[(size_t)(l * 32 + I1) * 4096 + cg0 + t] = s;
        }
    }
}

// ---------------- kernel 3: gather 32 partials/row -> loss; last block finalizes -----------
__global__ __launch_bounds__(256) void k_loss(const float* __restrict__ jv,
                                              const float* __restrict__ part,
                                              const float* __restrict__ diag,
                                              const float* __restrict__ pos,
                                              float* __restrict__ wsf,
                                              float* __restrict__ out) {
    __shared__ float sred[256];
    int tid = threadIdx.x;
    int r = blockIdx.x * 256 + tid;           // 64 blocks x 256 = 16384 rows
    int l = r >> 12, n = r & 4095;
    const float* pl = part + (size_t)l * 32 * 4096 + n;
    float s = 0.f;
    #pragma unroll
    for (int k = 0; k < 32; ++k) s += pl[(size_t)k * 4096];   // coalesced across lanes
    float denom = s - __builtin_amdgcn_exp2f(diag[r]);
    float contrib = LN2 * (__builtin_amdgcn_logf(denom) - pos[r]); // logf = v_log_f32 = log2
    float local = contrib * jv[n & (NHALF - 1)];
    sred[tid] = local; __syncthreads();
    for (int off = 128; off > 0; off >>= 1) {
        if (tid < off) sred[tid] += sred[tid + off];
        __syncthreads();
    }
    if (tid == 0) {
        atomicAdd(&wsf[0], sred[0]);
        __threadfence();                      // order loss-add before counter-add
        unsigned c = atomicAdd((unsigned*)&wsf[2], 1u);
        if (c == 63) {                        // 64th (last) block: finalize
            float tot = atomicAdd(&wsf[0], 0.f);   // device-scope coherent read
            out[0] = tot / (2.f * wsf[1]);
        }
    }
}

extern "C" void kernel_launch(void* const* d_in, const int* in_sizes, int n_in,
                              void* d_out, int out_size, void* d_ws, size_t ws_size,
                              hipStream_t stream) {
    const float* emb_i = (const float*)d_in[0];
    const float* emb_j = (const float*)d_in[1];
    const float* jv    = (const float*)d_in[2];
    float* wsf  = (float*)d_ws;
    float* part = wsf + WS_PART_OFF;
    float* diag = wsf + WS_DIAG_OFF;
    float* pos  = wsf + WS_POS_OFF;
    unsigned short* z = (unsigned short*)((char*)d_ws + WS_Z_BYTE_OFF);
    float* out = (float*)d_out;

    k_norm <<<4097, 256, 0, stream>>>(emb_i, emb_j, jv, wsf, z);
    k_sim  <<<1088, 256, 0, stream>>>(z, part, diag, pos);   // 4 l x 272 J-paired tiles
    k_loss <<<64,   256, 0, stream>>>(jv, part, diag, pos, wsf, out);
}

// Round 6
// 89.273 us; speedup vs baseline: 1.1139x; 1.1139x over previous
//
#include <hip/hip_runtime.h>
#include <hip/hip_bf16.h>

typedef __attribute__((ext_vector_type(8))) short short8;
typedef __attribute__((ext_vector_type(4))) float floatx4;

#define NROWS 4096
#define NHALF 2048
#define DDIM  128
#define LDST  136                 // LDS row stride in ushorts (128 + 8 pad -> 272B)
#define SQRT_SCALE 2.6857914f     // sqrt(1/(0.2*ln2)) ; dot of stored z == (sim/T)*log2(e)
#define LN2 0.69314718056f

// ws float layout: [0]=loss acc, [1]=all_num, [2]=k_loss completion counter,
// part [64, 64+4*32*4096) : part[l][k][n] = sum_{m in col-tile k} exp2(z_n . z_m)
//   slot k = column-tile index; for row n (row-tile R=n>>7): k>=R written by block (R,k)
//   row-side, k<R written by block (k,R) col-side -> EXACTLY ONE writer per element,
//   plain stores, no zero-init, no atomics.
#define WS_PART_OFF 64
#define WS_DIAG_OFF 524352        // 64 + 4*32*4096
#define WS_POS_OFF  540736        // + 16384
#define WS_Z_BYTE_OFF 2228480     // (WS_POS_OFF + 16384)*4, 16B aligned

__device__ inline unsigned short f2bf(float f) {
    unsigned u = __builtin_bit_cast(unsigned, f);
    u += 0x7fffu + ((u >> 16) & 1u);          // RNE
    return (unsigned short)(u >> 16);
}

// ---------------- kernel 1: normalize + scale + cast to bf16; zero scalars; all_num --------
__global__ __launch_bounds__(256) void k_norm(const float* __restrict__ emb_i,
                                              const float* __restrict__ emb_j,
                                              const float* __restrict__ jv,
                                              float* __restrict__ wsf,
                                              unsigned short* __restrict__ z) {
    int bx = blockIdx.x, tid = threadIdx.x;
    if (bx == 4096) {                         // all_num = sum(joint_valid)
        __shared__ float sred[256];
        float s = 0.f;
        #pragma unroll
        for (int i = 0; i < 8; ++i) s += jv[tid + 256 * i];
        sred[tid] = s; __syncthreads();
        for (int off = 128; off > 0; off >>= 1) {
            if (tid < off) sred[tid] += sred[tid + off];
            __syncthreads();
        }
        if (tid == 0) wsf[1] = sred[0];
        return;
    }
    if (bx == 0 && tid == 0) { wsf[0] = 0.f; *(unsigned*)&wsf[2] = 0u; }

    int wave = tid >> 6, lane = tid & 63;
    int r = bx * 4 + wave;                    // global row 0..16383
    int l = r >> 12, n = r & 4095;
    const float* src = (n < NHALF) ? (emb_i + ((size_t)l * NHALF + n) * DDIM)
                                   : (emb_j + ((size_t)l * NHALF + (n - NHALF)) * DDIM);
    float2 v = *(const float2*)(src + lane * 2);
    float ss = v.x * v.x + v.y * v.y;
    #pragma unroll
    for (int off = 1; off < 64; off <<= 1) ss += __shfl_xor(ss, off);
    float inv = SQRT_SCALE / fmaxf(sqrtf(ss), 1e-12f);
    unsigned pack = ((unsigned)f2bf(v.y * inv) << 16) | (unsigned)f2bf(v.x * inv);
    *(unsigned*)(z + (size_t)r * DDIM + lane * 2) = pack;
}

// ---------------- kernel 2: SYMMETRIC sim GEMM + exp2 sums, unique-writer stores -----------
// R5 post-mortem: pairing two tiles/block regressed (dual-chain state vs 168-VGPR cap ->
// R1-style pressure). R6 isolates the OTHER R5 variable: R4's exact single-tile 128x128
// structure (best measured, no spills, uncapped VGPR like R3) with atomics replaced by
// unique-writer part[] stores. Removes ~540k device-scope atomicAdds from k_sim's tail
// and the rowsum zero-init pass from k_norm.
// Upper-triangle of 32x32 tile grid: idx = J*(J+1)/2 + I, I<=J, 528 tiles per l.
// bx&3 = l pins each XCD to one l -> z working set 1MB, L2-resident.
__global__ __launch_bounds__(256) void k_sim(const unsigned short* __restrict__ z,
                                             float* __restrict__ part,
                                             float* __restrict__ diag,
                                             float* __restrict__ pos) {
    __shared__ __align__(16) unsigned short lds[128 * LDST];
    int bx = blockIdx.x, tid = threadIdx.x;
    int l = bx & 3, idx = bx >> 2;            // idx in [0,528)
    int J = (int)((sqrtf(8.f * (float)idx + 1.f) - 1.f) * 0.5f);
    while ((J + 1) * (J + 2) / 2 <= idx) ++J; // guard fp rounding
    while (J * (J + 1) / 2 > idx) --J;
    int I = idx - J * (J + 1) / 2;
    int wave = tid >> 6, lane = tid & 63, m = lane & 15, quad = lane >> 4;
    const unsigned short* zl = z + (size_t)l * NROWS * DDIM;
    int l4 = l * NROWS;
    int wr0 = I * 128 + wave * 32;            // 32 rows per wave
    int cg0 = J * 128;

    short8 a[2][4];                           // 2 row-subtiles x 4 k-steps
    #pragma unroll
    for (int rs = 0; rs < 2; ++rs) {
        const unsigned short* p = zl + (size_t)(wr0 + rs * 16 + m) * DDIM + quad * 8;
        #pragma unroll
        for (int kk = 0; kk < 4; ++kk) a[rs][kk] = *(const short8*)(p + kk * 32);
    }
    floatx4 rsum[2];
    #pragma unroll
    for (int rs = 0; rs < 2; ++rs) rsum[rs] = (floatx4){0.f, 0.f, 0.f, 0.f};
    float csum[8];                            // per-lane col partial, col = cs*16 + m
    #pragma unroll
    for (int g = 0; g < 8; ++g) csum[g] = 0.f;

    // stage 128x128 bf16 B-tile (cols cg0..cg0+127), 16B chunks, coalesced
    #pragma unroll
    for (int i = 0; i < 8; ++i) {
        int chunk = tid + 256 * i;
        int col = chunk >> 4, off = chunk & 15;
        uint4 d = *(const uint4*)(zl + (size_t)(cg0 + col) * DDIM + off * 8);
        *(uint4*)&lds[col * LDST + off * 8] = d;
    }
    __syncthreads();

    #pragma unroll
    for (int cs = 0; cs < 8; ++cs) {          // 16-col subtiles
        int ct = cg0 + cs * 16;               // tile column base (wave-uniform)
        const unsigned short* lp = &lds[(cs * 16 + m) * LDST + quad * 8];
        short8 b0 = *(const short8*)(lp);
        short8 b1 = *(const short8*)(lp + 32);
        short8 b2 = *(const short8*)(lp + 64);
        short8 b3 = *(const short8*)(lp + 96);
        #pragma unroll
        for (int rs = 0; rs < 2; ++rs) {
            floatx4 acc = (floatx4){0.f, 0.f, 0.f, 0.f};
            acc = __builtin_amdgcn_mfma_f32_16x16x32_bf16(a[rs][0], b0, acc, 0, 0, 0);
            acc = __builtin_amdgcn_mfma_f32_16x16x32_bf16(a[rs][1], b1, acc, 0, 0, 0);
            acc = __builtin_amdgcn_mfma_f32_16x16x32_bf16(a[rs][2], b2, acc, 0, 0, 0);
            acc = __builtin_amdgcn_mfma_f32_16x16x32_bf16(a[rs][3], b3, acc, 0, 0, 0);
            int rowbase = wr0 + rs * 16;
            bool isdiag = (ct == rowbase);          // only when I==J
            bool ispos  = (ct == rowbase + 2048);   // only when J==I+16
            if (isdiag || ispos) {            // rare, wave-uniform branch
                int c = m - (quad << 2);      // acc[c] holds sim[rowbase+quad*4+c][ct+m]
                if (c >= 0 && c < 4) {        // -> diagonal element iff quad*4+c == m
                    float v = acc[c];
                    if (isdiag) diag[l4 + rowbase + m] = v;
                    else {                    // sim[r, r+2048]; pos symmetric across halves
                        pos[l4 + rowbase + m] = v;
                        pos[l4 + rowbase + m + NHALF] = v;
                    }
                }
            }
            float t = 0.f;
            #pragma unroll
            for (int c = 0; c < 4; ++c) {
                float e = __builtin_amdgcn_exp2f(acc[c]);
                rsum[rs][c] += e;
                t += e;                       // sum over this lane's 4 rows
            }
            csum[cs] += t;                    // accumulate col partial across rs
        }
    }
    // row side: reduce across the 16 column-lanes; PLAIN STORES to slot J (unique writer)
    #pragma unroll
    for (int off = 1; off < 16; off <<= 1)
        #pragma unroll
        for (int rs = 0; rs < 2; ++rs)
            #pragma unroll
            for (int c = 0; c < 4; ++c)
                rsum[rs][c] += __shfl_xor(rsum[rs][c], off);
    float* plJ = part + (size_t)(l * 32 + J) * 4096;
    if (m == 0) {                             // lanes 0,16,32,48: rows wr0 + rs*16 + quad*4 + c
        #pragma unroll
        for (int rs = 0; rs < 2; ++rs)
            #pragma unroll
            for (int c = 0; c < 4; ++c)
                plJ[wr0 + rs * 16 + quad * 4 + c] = rsum[rs][c];
    }
    // col side (transpose contribution) -> slot I, off-diagonal tiles only
    if (I != J) {
        __syncthreads();                      // LDS tile dead; reuse as float reduce buffer
        float* cred = (float*)lds;            // [4 waves][128 cols]
        #pragma unroll
        for (int g = 0; g < 8; ++g) {         // finish reduce over the 16 rows (lane bits 4,5)
            float v = csum[g];
            v += __shfl_xor(v, 16);
            v += __shfl_xor(v, 32);
            if (quad == 0) cred[wave * 128 + g * 16 + m] = v;
        }
        __syncthreads();
        if (tid < 128) {
            float s = cred[tid] + cred[tid + 128] + cred[tid + 256] + cred[tid + 384];
            part[(size_t)(l * 32 + I) * 4096 + cg0 + tid] = s;  // plain store (unique writer)
        }
    }
}

// ---------------- kernel 3: gather 32 partials/row -> loss; last block finalizes -----------
__global__ __launch_bounds__(256) void k_loss(const float* __restrict__ jv,
                                              const float* __restrict__ part,
                                              const float* __restrict__ diag,
                                              const float* __restrict__ pos,
                                              float* __restrict__ wsf,
                                              float* __restrict__ out) {
    __shared__ float sred[256];
    int tid = threadIdx.x;
    int r = blockIdx.x * 256 + tid;           // 64 blocks x 256 = 16384 rows
    int l = r >> 12, n = r & 4095;
    const float* pl = part + (size_t)l * 32 * 4096 + n;
    float s = 0.f;
    #pragma unroll
    for (int k = 0; k < 32; ++k) s += pl[(size_t)k * 4096];   // coalesced across lanes
    float denom = s - __builtin_amdgcn_exp2f(diag[r]);
    float contrib = LN2 * (__builtin_amdgcn_logf(denom) - pos[r]); // logf = v_log_f32 = log2
    float local = contrib * jv[n & (NHALF - 1)];
    sred[tid] = local; __syncthreads();
    for (int off = 128; off > 0; off >>= 1) {
        if (tid < off) sred[tid] += sred[tid + off];
        __syncthreads();
    }
    if (tid == 0) {
        atomicAdd(&wsf[0], sred[0]);
        __threadfence();                      // order loss-add before counter-add
        unsigned c = atomicAdd((unsigned*)&wsf[2], 1u);
        if (c == 63) {                        // 64th (last) block: finalize
            float tot = atomicAdd(&wsf[0], 0.f);   // device-scope coherent read
            out[0] = tot / (2.f * wsf[1]);
        }
    }
}

extern "C" void kernel_launch(void* const* d_in, const int* in_sizes, int n_in,
                              void* d_out, int out_size, void* d_ws, size_t ws_size,
                              hipStream_t stream) {
    const float* emb_i = (const float*)d_in[0];
    const float* emb_j = (const float*)d_in[1];
    const float* jv    = (const float*)d_in[2];
    float* wsf  = (float*)d_ws;
    float* part = wsf + WS_PART_OFF;
    float* diag = wsf + WS_DIAG_OFF;
    float* pos  = wsf + WS_POS_OFF;
    unsigned short* z = (unsigned short*)((char*)d_ws + WS_Z_BYTE_OFF);
    float* out = (float*)d_out;

    k_norm <<<4097, 256, 0, stream>>>(emb_i, emb_j, jv, wsf, z);
    k_sim  <<<2112, 256, 0, stream>>>(z, part, diag, pos);   // 4 l x 528 upper-tri 128x128
    k_loss <<<64,   256, 0, stream>>>(jv, part, diag, pos, wsf, out);
}